// Round 7
// baseline (626.144 us; speedup 1.0000x reference)
//
#include <hip/hip_runtime.h>
#include <hip/hip_bf16.h>

typedef __hip_bfloat16 bf16;
typedef unsigned int uint;
typedef unsigned short ushort;
typedef __attribute__((ext_vector_type(8))) short short8;  // 8 x bf16 (4 VGPRs)
typedef __attribute__((ext_vector_type(4))) float floatx4;
typedef __attribute__((ext_vector_type(2))) float f32x2;

#define N_NODES 100000
#define N_PAD   100096   // multiple of 128 for the MFMA row tiling
#define E_EDGES 800000
#define NBLK    98       // ceil(N_NODES / 1024)
#define NSLICE  8        // one dst-slice per XCD (blockIdx % 8 ~ XCD id)
#define SLICE_N 12512    // ceil(N_NODES / NSLICE)
#define SLICE_BLOCKS 512 // blocks per slice row

static __device__ __forceinline__ uint packbf(float a, float b) {
  bf16 x = __float2bfloat16(a), y = __float2bfloat16(b);
  ushort ux = *reinterpret_cast<ushort*>(&x);
  ushort uy = *reinterpret_cast<ushort*>(&y);
  return (uint)ux | ((uint)uy << 16);
}
static __device__ __forceinline__ f32x2 unpk(uint u) {
  f32x2 r;
  r.x = __uint_as_float(u << 16);
  r.y = __uint_as_float(u & 0xffff0000u);
  return r;
}
static __device__ __forceinline__ f32x2 vmax2(f32x2 a, f32x2 b) {
#if __has_builtin(__builtin_elementwise_max)
  return __builtin_elementwise_max(a, b);
#else
  f32x2 r; r.x = fmaxf(a.x, b.x); r.y = fmaxf(a.y, b.y); return r;
#endif
}

// ---------------- CSR build (by destination), XCD-sliced ----------------
__global__ void hist_sliced_k(const int* __restrict__ dst0, const int* __restrict__ dst1,
                              int* dg0, int* dg1) {
  int slice = blockIdx.x & (NSLICE - 1);
  int blk = blockIdx.x >> 3;
  int lo = slice * SLICE_N, hi = lo + SLICE_N;
  for (int i = blk * 256 + threadIdx.x; i < E_EDGES; i += SLICE_BLOCKS * 256) {
    int d0 = dst0[i];
    if (d0 >= lo && d0 < hi) atomicAdd(&dg0[d0], 1);
    int d1 = dst1[i];
    if (d1 >= lo && d1 < hi) atomicAdd(&dg1[d1], 1);
  }
}

__global__ void scat_sliced_k(const int* __restrict__ src0, const int* __restrict__ dst0,
                              const int* __restrict__ src1, const int* __restrict__ dst1,
                              int* fi0, int* fi1, int* cs0, int* cs1) {
  int slice = blockIdx.x & (NSLICE - 1);
  int blk = blockIdx.x >> 3;
  int lo = slice * SLICE_N, hi = lo + SLICE_N;
  for (int i = blk * 256 + threadIdx.x; i < E_EDGES; i += SLICE_BLOCKS * 256) {
    int d0 = dst0[i];
    if (d0 >= lo && d0 < hi) { int p = atomicAdd(&fi0[d0], 1); cs0[p] = src0[i]; }
    int d1 = dst1[i];
    if (d1 >= lo && d1 < hi) { int p = atomicAdd(&fi1[d1], 1); cs1[p] = src1[i]; }
  }
}

__global__ void scan_blk_k(const int* __restrict__ deg0, const int* __restrict__ deg1,
                           int* rp0, int* rp1, int* bsum) {
  __shared__ int s[1024];
  int r = blockIdx.y;
  const int* deg = r ? deg1 : deg0;
  int* rp = r ? rp1 : rp0;
  int i = blockIdx.x * 1024 + threadIdx.x;
  int v = (i < N_NODES) ? deg[i] : 0;
  s[threadIdx.x] = v;
  __syncthreads();
  for (int off = 1; off < 1024; off <<= 1) {
    int t = (threadIdx.x >= off) ? s[threadIdx.x - off] : 0;
    __syncthreads();
    s[threadIdx.x] += t;
    __syncthreads();
  }
  if (i < N_NODES) rp[i] = s[threadIdx.x] - v;
  if (threadIdx.x == 1023) bsum[r * NBLK + blockIdx.x] = s[1023];
}

__global__ void scan_top_k(int* bsum, int* rp0, int* rp1) {
  __shared__ int s[128];
  int r = blockIdx.x;
  int v = (threadIdx.x < NBLK) ? bsum[r * NBLK + threadIdx.x] : 0;
  s[threadIdx.x] = v;
  __syncthreads();
  for (int off = 1; off < 128; off <<= 1) {
    int t = (threadIdx.x >= off) ? s[threadIdx.x - off] : 0;
    __syncthreads();
    s[threadIdx.x] += t;
    __syncthreads();
  }
  if (threadIdx.x < NBLK) bsum[r * NBLK + threadIdx.x] = s[threadIdx.x] - v;
  if (threadIdx.x == 127) (r ? rp1 : rp0)[N_NODES] = s[127];
}

__global__ void scan_add_k(const int* __restrict__ bsum,
                           int* rp0, int* rp1, int* fi0, int* fi1) {
  int r = blockIdx.y;
  int i = blockIdx.x * 1024 + threadIdx.x;
  if (i >= N_NODES) return;
  int* rp = r ? rp1 : rp0;
  int* fi = r ? fi1 : fi0;
  int val = rp[i] + bsum[r * NBLK + blockIdx.x];
  rp[i] = val;
  fi[i] = val;
}

// ---------------- layer-1 transforms (K=2) ----------------
// fused: one block per node, 256 thr = 2 rel x 2 side x 64 ch-pairs
__global__ void t1f_k(const float* __restrict__ x,
                      const float* __restrict__ Wl, const float* __restrict__ bl,
                      const float* __restrict__ Wr, const float* __restrict__ br,
                      bf16* __restrict__ XL0, bf16* __restrict__ XR0,
                      bf16* __restrict__ XL1, bf16* __restrict__ XR1) {
  int node = blockIdx.x;
  int t = threadIdx.x;
  int rel = t >> 7, side = (t >> 6) & 1, p = t & 63;
  int c0 = 2 * p;
  const float* W = (side ? Wr : Wl) + rel * 256;
  const float* B = (side ? br : bl) + rel * 128;
  bf16* X = rel ? (side ? XR1 : XL1) : (side ? XR0 : XL0);
  float x0 = x[node * 2], x1 = x[node * 2 + 1];
  float v0 = B[c0]     + x0 * W[c0]     + x1 * W[128 + c0];
  float v1 = B[c0 + 1] + x0 * W[c0 + 1] + x1 * W[128 + c0 + 1];
  *(uint*)(X + (size_t)node * 128 + c0) = packbf(v0, v1);
}

// per-relation variant (fallback path)
__global__ void t1_k(const float* __restrict__ x,
                     const float* __restrict__ Wl, const float* __restrict__ blp,
                     const float* __restrict__ Wr, const float* __restrict__ brp,
                     bf16* __restrict__ XL, bf16* __restrict__ XR) {
  int t = threadIdx.x;
  int node = blockIdx.x * 2 + (t >> 7);
  if (node >= N_NODES) return;
  int qq = t & 127;
  int side = qq >> 6;
  int p = qq & 63;
  int c0 = 2 * p;
  const float* W = side ? Wr : Wl;
  const float* B = side ? brp : blp;
  bf16* X = side ? XR : XL;
  float x0 = x[node * 2], x1 = x[node * 2 + 1];
  float v0 = B[c0]     + x0 * W[c0]     + x1 * W[128 + c0];
  float v1 = B[c0 + 1] + x0 * W[c0 + 1] + x1 * W[128 + c0 + 1];
  *(uint*)(X + (size_t)node * 128 + c0) = packbf(v0, v1);
}

// ---------------- layer-2 weight prep: WT[rel][c][k] bf16 (transposed) ----------------
__global__ void wprep_k(const float* __restrict__ Wl, const float* __restrict__ Wr,
                        short* __restrict__ WT) {
  int id2 = blockIdx.x * 256 + threadIdx.x;
  int rel = id2 >> 14;
  int id = id2 & 16383;
  int c = id >> 6, k = id & 63;
  const float* W = (c < 128) ? (Wl + rel * 8192) : (Wr + rel * 8192);
  int cc = c & 127;
  bf16 b = __float2bfloat16(W[k * 128 + cc]);
  WT[rel * 16384 + c * 64 + k] = *reinterpret_cast<short*>(&b);
}

// ---------------- layer-2 transform: XL/XR = HB @ WT^T, MFMA 16x16x32 ----------------
__global__ __launch_bounds__(256) void mfma_t_k(const bf16* __restrict__ HB,
                                                const short* __restrict__ WT,
                                                const float* __restrict__ bl,
                                                const float* __restrict__ br,
                                                bf16* __restrict__ XL,
                                                bf16* __restrict__ XR) {
  __shared__ short sW[256 * 72];
  int t = threadIdx.x;
#pragma unroll
  for (int i = 0; i < 8; ++i) {
    int chunk = t + i * 256;
    int c = chunk >> 3, off = (chunk & 7) * 8;
    *(short8*)(&sW[c * 72 + off]) = *(const short8*)(WT + chunk * 8);
  }
  __syncthreads();
  int wave = t >> 6, lane = t & 63;
  int q = lane >> 4, m = lane & 15;
  int rowbase = blockIdx.x * 128 + wave * 32;
  short8 afr[2][2];
#pragma unroll
  for (int rt = 0; rt < 2; ++rt)
#pragma unroll
    for (int kh = 0; kh < 2; ++kh) {
      size_t row = (size_t)(rowbase + rt * 16 + m);
      afr[rt][kh] = *(const short8*)((const short*)HB + row * 64 + kh * 32 + q * 8);
    }
  for (int ct = 0; ct < 16; ++ct) {
    int col = ct * 16 + m;
    short8 b0 = *(const short8*)(&sW[col * 72 + q * 8]);
    short8 b1 = *(const short8*)(&sW[col * 72 + 32 + q * 8]);
    float bias = (col < 128) ? bl[col] : br[col - 128];
    bf16* X = (col < 128) ? XL : XR;
    int c128 = col & 127;
#pragma unroll
    for (int rt = 0; rt < 2; ++rt) {
      floatx4 acc = {0.f, 0.f, 0.f, 0.f};
      acc = __builtin_amdgcn_mfma_f32_16x16x32_bf16(afr[rt][0], b0, acc, 0, 0, 0);
      acc = __builtin_amdgcn_mfma_f32_16x16x32_bf16(afr[rt][1], b1, acc, 0, 0, 0);
      int r0 = rowbase + rt * 16 + q * 4;
#pragma unroll
      for (int i2 = 0; i2 < 4; ++i2) {
        int row = r0 + i2;
        if (row < N_NODES)
          X[(size_t)row * 128 + c128] = __float2bfloat16(acc[i2] + bias);
      }
    }
  }
}

// ---------------- fused agg: 16 lanes/edge, 4 edges/wave, packed-f32 math ----------------
// wave = 1 dst node. slot = lane>>4 takes edges beg+slot, +4, ... ; lane covers
// 8 channels (16 B) of the 256 B row. Head0 = slot-lanes 0..7, head1 = 8..15.
static __device__ __forceinline__ void stepv(uint4 u, const f32x2* xr, const f32x2* at,
                                             f32x2* acc, float& den) {
  f32x2 x0 = unpk(u.x), x1 = unpk(u.y), x2 = unpk(u.z), x3 = unpk(u.w);
  f32x2 e0 = x0 + xr[0]; e0 = vmax2(e0, 0.2f * e0);
  f32x2 e1 = x1 + xr[1]; e1 = vmax2(e1, 0.2f * e1);
  f32x2 e2 = x2 + xr[2]; e2 = vmax2(e2, 0.2f * e2);
  f32x2 e3 = x3 + xr[3]; e3 = vmax2(e3, 0.2f * e3);
  f32x2 p2 = e0 * at[0] + e1 * at[1] + e2 * at[2] + e3 * at[3];
  float p = p2.x + p2.y;
  p += __shfl_xor(p, 1);
  p += __shfl_xor(p, 2);
  p += __shfl_xor(p, 4);     // 8-lane head-group score (slot-local)
  float ex = __expf(p);
  den += ex;
  acc[0] += ex * x0; acc[1] += ex * x1; acc[2] += ex * x2; acc[3] += ex * x3;
}

// nrel=2: both relations, write final. nrel=1: single relation (ptr set 0);
// phase 0 stores partial to accum, phase 1 combines accum with this relation.
__global__ __launch_bounds__(256) void aggv_k(
    const int* __restrict__ rp0, const int* __restrict__ cs0,
    const bf16* __restrict__ XL0, const bf16* __restrict__ XR0,
    const int* __restrict__ rp1, const int* __restrict__ cs1,
    const bf16* __restrict__ XL1, const bf16* __restrict__ XR1,
    const float* __restrict__ att0, const float* __restrict__ att1,
    const float* __restrict__ bias0, const float* __restrict__ bias1,
    float* __restrict__ accum, uint4* __restrict__ hout, float* __restrict__ outf,
    int nrel, int phase, int do_relu) {
  int d = (blockIdx.x * 256 + threadIdx.x) >> 6;
  int lane = threadIdx.x & 63;
  if (d >= N_NODES) return;
  int slot = lane >> 4, sl = lane & 15;
  f32x2 po[4], o[4];
  for (int r = 0; r < nrel; ++r) {
    const int* rp = r ? rp1 : rp0;
    const int* cs = r ? cs1 : cs0;
    const bf16* XL = r ? XL1 : XL0;
    const bf16* XR = r ? XR1 : XR0;
    const float* att = r ? att1 : att0;
    uint4 ux = *(const uint4*)(XR + (size_t)d * 128 + 8 * sl);
    f32x2 xr[4] = {unpk(ux.x), unpk(ux.y), unpk(ux.z), unpk(ux.w)};
    f32x2 at[4];
    {
      const float* ap = att + 8 * sl;
      float4 q0 = *(const float4*)ap, q1 = *(const float4*)(ap + 4);
      at[0].x = q0.x; at[0].y = q0.y; at[1].x = q0.z; at[1].y = q0.w;
      at[2].x = q1.x; at[2].y = q1.y; at[3].x = q1.z; at[3].y = q1.w;
    }
    f32x2 acc[4];
    acc[0] = 0.f; acc[1] = 0.f; acc[2] = 0.f; acc[3] = 0.f;
    float den = 0.f;
    int beg = rp[d], end = rp[d + 1];
    int j = beg + slot;
    for (; j + 4 < end; j += 8) {   // 2 independent gathers in flight
      int sA = cs[j], sB = cs[j + 4];
      uint4 uA = *(const uint4*)(XL + (size_t)sA * 128 + 8 * sl);
      uint4 uB = *(const uint4*)(XL + (size_t)sB * 128 + 8 * sl);
      stepv(uA, xr, at, acc, den);
      stepv(uB, xr, at, acc, den);
    }
    if (j < end) {
      int sA = cs[j];
      uint4 uA = *(const uint4*)(XL + (size_t)sA * 128 + 8 * sl);
      stepv(uA, xr, at, acc, den);
    }
    // combine the 4 edge slots
    den += __shfl_xor(den, 16); den += __shfl_xor(den, 32);
#pragma unroll
    for (int i = 0; i < 4; ++i) {
      acc[i].x += __shfl_xor(acc[i].x, 16);
      acc[i].y += __shfl_xor(acc[i].y, 16);
      acc[i].x += __shfl_xor(acc[i].x, 32);
      acc[i].y += __shfl_xor(acc[i].y, 32);
    }
    float inv = 1.f / (den + 1e-16f);   // per-head denom (sl<8: h0, sl>=8: h1)
    const float* bp = (r ? bias1 : bias0) + 8 * (sl & 7);
    float4 b0 = *(const float4*)bp, b1 = *(const float4*)(bp + 4);
#pragma unroll
    for (int i = 0; i < 4; ++i) {
      f32x2 a = acc[i] * inv;
      f32x2 hm;
      hm.x = a.x + __shfl_xor(a.x, 8);   // head mean (valid for sl<8)
      hm.y = a.y + __shfl_xor(a.y, 8);
      o[i] = 0.5f * hm;
    }
    o[0].x += b0.x; o[0].y += b0.y; o[1].x += b0.z; o[1].y += b0.w;
    o[2].x += b1.x; o[2].y += b1.y; o[3].x += b1.z; o[3].y += b1.w;
    if (r == 0) { po[0] = o[0]; po[1] = o[1]; po[2] = o[2]; po[3] = o[3]; }
  }
  if (lane >= 8) return;
  size_t oi = (size_t)d * 64 + 8 * lane;
  f32x2 v[4];
  if (nrel == 2) {
#pragma unroll
    for (int i = 0; i < 4; ++i) v[i] = 0.5f * (po[i] + o[i]);
  } else if (phase == 0) {
    *(float4*)(accum + oi) = make_float4(po[0].x, po[0].y, po[1].x, po[1].y);
    *(float4*)(accum + oi + 4) = make_float4(po[2].x, po[2].y, po[3].x, po[3].y);
    return;
  } else {
    float4 pa0 = *(const float4*)(accum + oi);
    float4 pa1 = *(const float4*)(accum + oi + 4);
    v[0].x = 0.5f * (pa0.x + po[0].x); v[0].y = 0.5f * (pa0.y + po[0].y);
    v[1].x = 0.5f * (pa0.z + po[1].x); v[1].y = 0.5f * (pa0.w + po[1].y);
    v[2].x = 0.5f * (pa1.x + po[2].x); v[2].y = 0.5f * (pa1.y + po[2].y);
    v[3].x = 0.5f * (pa1.z + po[3].x); v[3].y = 0.5f * (pa1.w + po[3].y);
  }
  if (do_relu) {
#pragma unroll
    for (int i = 0; i < 4; ++i) v[i] = vmax2(v[i], f32x2{0.f, 0.f});
  }
  if (outf) {
    *(float4*)(outf + oi) = make_float4(v[0].x, v[0].y, v[1].x, v[1].y);
    *(float4*)(outf + oi + 4) = make_float4(v[2].x, v[2].y, v[3].x, v[3].y);
  } else {
    uint4 pk;
    pk.x = packbf(v[0].x, v[0].y); pk.y = packbf(v[1].x, v[1].y);
    pk.z = packbf(v[2].x, v[2].y); pk.w = packbf(v[3].x, v[3].y);
    hout[(size_t)d * 8 + lane] = pk;
  }
}

extern "C" void kernel_launch(void* const* d_in, const int* in_sizes, int n_in,
                              void* d_out, int out_size, void* d_ws, size_t ws_size,
                              hipStream_t stream) {
  const float* x       = (const float*)d_in[0];
  const int*   e_adj   = (const int*)d_in[1];
  const int*   e_ray   = (const int*)d_in[2];
  const float* l1_Wl   = (const float*)d_in[3];
  const float* l1_bl   = (const float*)d_in[4];
  const float* l1_Wr   = (const float*)d_in[5];
  const float* l1_br   = (const float*)d_in[6];
  const float* l1_att  = (const float*)d_in[7];
  const float* l1_bias = (const float*)d_in[8];
  const float* l2_Wl   = (const float*)d_in[9];
  const float* l2_bl   = (const float*)d_in[10];
  const float* l2_Wr   = (const float*)d_in[11];
  const float* l2_br   = (const float*)d_in[12];
  const float* l2_att  = (const float*)d_in[13];
  const float* l2_bias = (const float*)d_in[14];
  float* out = (float*)d_out;

  char* w = (char*)d_ws;
  size_t off = 0;
  auto alloc = [&](size_t bytes) -> char* {
    char* p = w + off;
    off += (bytes + 255) & ~(size_t)255;
    return p;
  };
  // base set (~74 MB) — fallback uses only these
  bf16* XL0  = (bf16*)alloc((size_t)N_PAD * 128 * 2);
  bf16* XR0  = (bf16*)alloc((size_t)N_PAD * 128 * 2);
  bf16* HB   = (bf16*)alloc((size_t)N_PAD * 64 * 2);
  short* WT  = (short*)alloc(2 * 16384 * 2);
  int* RP0   = (int*)alloc((size_t)(N_NODES + 1) * 4);
  int* RP1   = (int*)alloc((size_t)(N_NODES + 1) * 4);
  int* FI0   = (int*)alloc((size_t)N_NODES * 4);
  int* FI1   = (int*)alloc((size_t)N_NODES * 4);
  int* CS0   = (int*)alloc((size_t)E_EDGES * 4);
  int* CS1   = (int*)alloc((size_t)E_EDGES * 4);
  int* DG0   = (int*)alloc((size_t)N_NODES * 4);
  int* DG1   = (int*)alloc((size_t)N_NODES * 4);
  int* BSUM  = (int*)alloc(2 * NBLK * 4);
  // extra relation-1 buffers (fused path only, ~+51 MB)
  bf16* XL1  = (bf16*)alloc((size_t)N_PAD * 128 * 2);
  bf16* XR1  = (bf16*)alloc((size_t)N_PAD * 128 * 2);
  const bool fused = (ws_size >= off);
  if (!fused) { XL1 = XL0; XR1 = XR0; }
  float* ACC = out;  // fallback relation-partial; read-before-write per element

  const int* src_adj = e_adj;
  const int* dst_adj = e_adj + E_EDGES;
  const int* src_ray = e_ray;
  const int* dst_ray = e_ray + E_EDGES;

  const int WNB = (N_NODES * 64) / 256;    // 25000 (one wave per node)
  const int MB  = N_PAD / 128;             // 782
  const int SB  = SLICE_BLOCKS * NSLICE;   // 4096

  // CSR build (shared by both layers)
  size_t dgspan = (size_t)((char*)DG1 - (char*)DG0) + (size_t)N_NODES * 4;
  hipMemsetAsync(DG0, 0, dgspan, stream);
  hist_sliced_k<<<SB, 256, 0, stream>>>(dst_adj, dst_ray, DG0, DG1);
  scan_blk_k<<<dim3(NBLK, 2), 1024, 0, stream>>>(DG0, DG1, RP0, RP1, BSUM);
  scan_top_k<<<2, 128, 0, stream>>>(BSUM, RP0, RP1);
  scan_add_k<<<dim3(NBLK, 2), 1024, 0, stream>>>(BSUM, RP0, RP1, FI0, FI1);
  scat_sliced_k<<<SB, 256, 0, stream>>>(src_adj, dst_adj, src_ray, dst_ray,
                                        FI0, FI1, CS0, CS1);
  wprep_k<<<128, 256, 0, stream>>>(l2_Wl, l2_Wr, WT);

  if (fused) {
    // layer 1: both relations in one transform + one agg
    t1f_k<<<N_NODES, 256, 0, stream>>>(x, l1_Wl, l1_bl, l1_Wr, l1_br,
                                       XL0, XR0, XL1, XR1);
    aggv_k<<<WNB, 256, 0, stream>>>(RP0, CS0, XL0, XR0, RP1, CS1, XL1, XR1,
                                    l1_att, l1_att + 128, l1_bias, l1_bias + 64,
                                    nullptr, (uint4*)HB, nullptr, 2, 0, 1);
    // layer 2
    mfma_t_k<<<MB, 256, 0, stream>>>(HB, WT, l2_bl, l2_br, XL0, XR0);
    mfma_t_k<<<MB, 256, 0, stream>>>(HB, WT + 16384, l2_bl + 128, l2_br + 128,
                                     XL1, XR1);
    aggv_k<<<WNB, 256, 0, stream>>>(RP0, CS0, XL0, XR0, RP1, CS1, XL1, XR1,
                                    l2_att, l2_att + 128, l2_bias, l2_bias + 64,
                                    nullptr, nullptr, out, 2, 0, 0);
  } else {
    const int TNB = (N_NODES + 1) / 2;
    for (int r = 0; r < 2; ++r) {
      const int* rp = r ? RP1 : RP0;
      const int* cs = r ? CS1 : CS0;
      t1_k<<<TNB, 256, 0, stream>>>(x, l1_Wl + r * 256, l1_bl + r * 128,
                                    l1_Wr + r * 256, l1_br + r * 128, XL0, XR0);
      aggv_k<<<WNB, 256, 0, stream>>>(rp, cs, XL0, XR0, rp, cs, XL0, XR0,
                                      l1_att + r * 128, l1_att + r * 128,
                                      l1_bias + r * 64, l1_bias + r * 64,
                                      ACC, (uint4*)HB, nullptr, 1, r, 1);
    }
    for (int r = 0; r < 2; ++r) {
      const int* rp = r ? RP1 : RP0;
      const int* cs = r ? CS1 : CS0;
      mfma_t_k<<<MB, 256, 0, stream>>>(HB, WT + r * 16384, l2_bl + r * 128,
                                       l2_br + r * 128, XL0, XR0);
      aggv_k<<<WNB, 256, 0, stream>>>(rp, cs, XL0, XR0, rp, cs, XL0, XR0,
                                      l2_att + r * 128, l2_att + r * 128,
                                      l2_bias + r * 64, l2_bias + r * 64,
                                      ACC, nullptr, out, 1, r, 0);
    }
  }
}

// Round 8
// 582.597 us; speedup vs baseline: 1.0747x; 1.0747x over previous
//
#include <hip/hip_runtime.h>
#include <hip/hip_bf16.h>

typedef __hip_bfloat16 bf16;
typedef unsigned int uint;
typedef unsigned short ushort;
typedef __attribute__((ext_vector_type(8))) short short8;  // 8 x bf16 (4 VGPRs)
typedef __attribute__((ext_vector_type(4))) float floatx4;
typedef __attribute__((ext_vector_type(2))) float f32x2;

#define N_NODES 100000
#define N_PAD   100096   // multiple of 128 for the MFMA row tiling
#define E_EDGES 800000
#define NBLK    98       // ceil(N_NODES / 1024)
#define NSLICE  8        // one dst-slice per XCD (blockIdx % 8 ~ XCD id)
#define SLICE_N 12512    // ceil(N_NODES / NSLICE)
#define SLICE_BLOCKS 512 // blocks per slice row

static __device__ __forceinline__ uint packbf(float a, float b) {
  bf16 x = __float2bfloat16(a), y = __float2bfloat16(b);
  ushort ux = *reinterpret_cast<ushort*>(&x);
  ushort uy = *reinterpret_cast<ushort*>(&y);
  return (uint)ux | ((uint)uy << 16);
}
static __device__ __forceinline__ f32x2 unpk(uint u) {
  f32x2 r;
  r.x = __uint_as_float(u << 16);
  r.y = __uint_as_float(u & 0xffff0000u);
  return r;
}
static __device__ __forceinline__ f32x2 vmax2(f32x2 a, f32x2 b) {
#if __has_builtin(__builtin_elementwise_max)
  return __builtin_elementwise_max(a, b);
#else
  f32x2 r; r.x = fmaxf(a.x, b.x); r.y = fmaxf(a.y, b.y); return r;
#endif
}

// ---------------- CSR build (by destination), XCD-sliced ----------------
__global__ void hist_sliced_k(const int* __restrict__ dst0, const int* __restrict__ dst1,
                              int* dg0, int* dg1) {
  int slice = blockIdx.x & (NSLICE - 1);
  int blk = blockIdx.x >> 3;
  int lo = slice * SLICE_N, hi = lo + SLICE_N;
  for (int i = blk * 256 + threadIdx.x; i < E_EDGES; i += SLICE_BLOCKS * 256) {
    int d0 = dst0[i];
    if (d0 >= lo && d0 < hi) atomicAdd(&dg0[d0], 1);
    int d1 = dst1[i];
    if (d1 >= lo && d1 < hi) atomicAdd(&dg1[d1], 1);
  }
}

__global__ void scat_sliced_k(const int* __restrict__ src0, const int* __restrict__ dst0,
                              const int* __restrict__ src1, const int* __restrict__ dst1,
                              int* fi0, int* fi1, int* cs0, int* cs1) {
  int slice = blockIdx.x & (NSLICE - 1);
  int blk = blockIdx.x >> 3;
  int lo = slice * SLICE_N, hi = lo + SLICE_N;
  for (int i = blk * 256 + threadIdx.x; i < E_EDGES; i += SLICE_BLOCKS * 256) {
    int d0 = dst0[i];
    if (d0 >= lo && d0 < hi) { int p = atomicAdd(&fi0[d0], 1); cs0[p] = src0[i]; }
    int d1 = dst1[i];
    if (d1 >= lo && d1 < hi) { int p = atomicAdd(&fi1[d1], 1); cs1[p] = src1[i]; }
  }
}

__global__ void scan_blk_k(const int* __restrict__ deg0, const int* __restrict__ deg1,
                           int* rp0, int* rp1, int* bsum) {
  __shared__ int s[1024];
  int r = blockIdx.y;
  const int* deg = r ? deg1 : deg0;
  int* rp = r ? rp1 : rp0;
  int i = blockIdx.x * 1024 + threadIdx.x;
  int v = (i < N_NODES) ? deg[i] : 0;
  s[threadIdx.x] = v;
  __syncthreads();
  for (int off = 1; off < 1024; off <<= 1) {
    int t = (threadIdx.x >= off) ? s[threadIdx.x - off] : 0;
    __syncthreads();
    s[threadIdx.x] += t;
    __syncthreads();
  }
  if (i < N_NODES) rp[i] = s[threadIdx.x] - v;
  if (threadIdx.x == 1023) bsum[r * NBLK + blockIdx.x] = s[1023];
}

__global__ void scan_top_k(int* bsum, int* rp0, int* rp1) {
  __shared__ int s[128];
  int r = blockIdx.x;
  int v = (threadIdx.x < NBLK) ? bsum[r * NBLK + threadIdx.x] : 0;
  s[threadIdx.x] = v;
  __syncthreads();
  for (int off = 1; off < 128; off <<= 1) {
    int t = (threadIdx.x >= off) ? s[threadIdx.x - off] : 0;
    __syncthreads();
    s[threadIdx.x] += t;
    __syncthreads();
  }
  if (threadIdx.x < NBLK) bsum[r * NBLK + threadIdx.x] = s[threadIdx.x] - v;
  if (threadIdx.x == 127) (r ? rp1 : rp0)[N_NODES] = s[127];
}

__global__ void scan_add_k(const int* __restrict__ bsum,
                           int* rp0, int* rp1, int* fi0, int* fi1) {
  int r = blockIdx.y;
  int i = blockIdx.x * 1024 + threadIdx.x;
  if (i >= N_NODES) return;
  int* rp = r ? rp1 : rp0;
  int* fi = r ? fi1 : fi0;
  int val = rp[i] + bsum[r * NBLK + blockIdx.x];
  rp[i] = val;
  fi[i] = val;
}

// ---------------- layer-1 transform (K=2), both relations, one dispatch ----------------
__global__ void t1f_k(const float* __restrict__ x,
                      const float* __restrict__ Wl, const float* __restrict__ bl,
                      const float* __restrict__ Wr, const float* __restrict__ br,
                      bf16* __restrict__ XL0, bf16* __restrict__ XR0,
                      bf16* __restrict__ XL1, bf16* __restrict__ XR1) {
  int node = blockIdx.x;
  int t = threadIdx.x;
  int rel = t >> 7, side = (t >> 6) & 1, p = t & 63;
  int c0 = 2 * p;
  const float* W = (side ? Wr : Wl) + rel * 256;
  const float* B = (side ? br : bl) + rel * 128;
  bf16* X = rel ? (side ? XR1 : XL1) : (side ? XR0 : XL0);
  float x0 = x[node * 2], x1 = x[node * 2 + 1];
  float v0 = B[c0]     + x0 * W[c0]     + x1 * W[128 + c0];
  float v1 = B[c0 + 1] + x0 * W[c0 + 1] + x1 * W[128 + c0 + 1];
  *(uint*)(X + (size_t)node * 128 + c0) = packbf(v0, v1);
}

// ---------------- layer-2 weight prep: WT[rel][c][k] bf16 (transposed) ----------------
__global__ void wprep_k(const float* __restrict__ Wl, const float* __restrict__ Wr,
                        short* __restrict__ WT) {
  int id2 = blockIdx.x * 256 + threadIdx.x;
  int rel = id2 >> 14;
  int id = id2 & 16383;
  int c = id >> 6, k = id & 63;
  const float* W = (c < 128) ? (Wl + rel * 8192) : (Wr + rel * 8192);
  int cc = c & 127;
  bf16 b = __float2bfloat16(W[k * 128 + cc]);
  WT[rel * 16384 + c * 64 + k] = *reinterpret_cast<short*>(&b);
}

// ---------------- layer-2 transform, both relations via blockIdx.z ----------------
__global__ __launch_bounds__(256) void mfma_t_k(const bf16* __restrict__ HB,
                                                const short* __restrict__ WTb,
                                                const float* __restrict__ blb,
                                                const float* __restrict__ brb,
                                                bf16* __restrict__ XL0,
                                                bf16* __restrict__ XR0,
                                                bf16* __restrict__ XL1,
                                                bf16* __restrict__ XR1) {
  __shared__ short sW[256 * 72];
  int rel = blockIdx.z;
  const short* WT = WTb + rel * 16384;
  const float* bl = blb + rel * 128;
  const float* br = brb + rel * 128;
  bf16* XLp = rel ? XL1 : XL0;
  bf16* XRp = rel ? XR1 : XR0;
  int t = threadIdx.x;
#pragma unroll
  for (int i = 0; i < 8; ++i) {
    int chunk = t + i * 256;
    int c = chunk >> 3, off = (chunk & 7) * 8;
    *(short8*)(&sW[c * 72 + off]) = *(const short8*)(WT + chunk * 8);
  }
  __syncthreads();
  int wave = t >> 6, lane = t & 63;
  int q = lane >> 4, m = lane & 15;
  int rowbase = blockIdx.x * 128 + wave * 32;
  short8 afr[2][2];
#pragma unroll
  for (int rt = 0; rt < 2; ++rt)
#pragma unroll
    for (int kh = 0; kh < 2; ++kh) {
      size_t row = (size_t)(rowbase + rt * 16 + m);
      afr[rt][kh] = *(const short8*)((const short*)HB + row * 64 + kh * 32 + q * 8);
    }
  for (int ct = 0; ct < 16; ++ct) {
    int col = ct * 16 + m;
    short8 b0 = *(const short8*)(&sW[col * 72 + q * 8]);
    short8 b1 = *(const short8*)(&sW[col * 72 + 32 + q * 8]);
    float bias = (col < 128) ? bl[col] : br[col - 128];
    bf16* X = (col < 128) ? XLp : XRp;
    int c128 = col & 127;
#pragma unroll
    for (int rt = 0; rt < 2; ++rt) {
      floatx4 acc = {0.f, 0.f, 0.f, 0.f};
      acc = __builtin_amdgcn_mfma_f32_16x16x32_bf16(afr[rt][0], b0, acc, 0, 0, 0);
      acc = __builtin_amdgcn_mfma_f32_16x16x32_bf16(afr[rt][1], b1, acc, 0, 0, 0);
      int r0 = rowbase + rt * 16 + q * 4;
#pragma unroll
      for (int i2 = 0; i2 < 4; ++i2) {
        int row = r0 + i2;
        if (row < N_NODES)
          X[(size_t)row * 128 + c128] = __float2bfloat16(acc[i2] + bias);
      }
    }
  }
}

// ---------------- single-relation agg: 16 lanes/edge, 4 edges/wave, packed f32 ----------------
// wave = 1 dst node; slot = lane>>4 takes edges beg+slot, beg+slot+4, ...;
// lane covers 8 channels (16 B) of the 256 B row. head0 = sl 0..7, head1 = sl 8..15.
static __device__ __forceinline__ void stepv(uint4 u, const f32x2* xr, const f32x2* at,
                                             f32x2* acc, float& den) {
  f32x2 x0 = unpk(u.x), x1 = unpk(u.y), x2 = unpk(u.z), x3 = unpk(u.w);
  f32x2 e0 = x0 + xr[0]; e0 = vmax2(e0, 0.2f * e0);
  f32x2 e1 = x1 + xr[1]; e1 = vmax2(e1, 0.2f * e1);
  f32x2 e2 = x2 + xr[2]; e2 = vmax2(e2, 0.2f * e2);
  f32x2 e3 = x3 + xr[3]; e3 = vmax2(e3, 0.2f * e3);
  f32x2 p2 = e0 * at[0] + e1 * at[1] + e2 * at[2] + e3 * at[3];
  float p = p2.x + p2.y;
  p += __shfl_xor(p, 1);
  p += __shfl_xor(p, 2);
  p += __shfl_xor(p, 4);     // 8-lane head-group score (slot-local)
  float ex = __expf(p);
  den += ex;
  acc[0] += ex * x0; acc[1] += ex * x1; acc[2] += ex * x2; acc[3] += ex * x3;
}

// phase 0: write fp32 partial to accum. phase 1: combine, 0.5x relation mean,
// optional relu, write bf16-packed hout or fp32 outf.
__global__ __launch_bounds__(256) void agg1_k(
    const int* __restrict__ rp, const int* __restrict__ cs,
    const bf16* __restrict__ XL, const bf16* __restrict__ XR,
    const float* __restrict__ att, const float* __restrict__ bias,
    float* __restrict__ accum, uint4* __restrict__ hout, float* __restrict__ outf,
    int phase, int do_relu) {
  int d = (blockIdx.x * 256 + threadIdx.x) >> 6;
  int lane = threadIdx.x & 63;
  if (d >= N_NODES) return;
  int slot = lane >> 4, sl = lane & 15;
  uint4 ux = *(const uint4*)(XR + (size_t)d * 128 + 8 * sl);
  f32x2 xr[4] = {unpk(ux.x), unpk(ux.y), unpk(ux.z), unpk(ux.w)};
  f32x2 at[4];
  {
    const float* ap = att + 8 * sl;
    float4 q0 = *(const float4*)ap, q1 = *(const float4*)(ap + 4);
    at[0].x = q0.x; at[0].y = q0.y; at[1].x = q0.z; at[1].y = q0.w;
    at[2].x = q1.x; at[2].y = q1.y; at[3].x = q1.z; at[3].y = q1.w;
  }
  f32x2 acc[4];
  acc[0] = 0.f; acc[1] = 0.f; acc[2] = 0.f; acc[3] = 0.f;
  float den = 0.f;
  int beg = rp[d], end = rp[d + 1];
  int j = beg + slot;
  for (; j + 4 < end; j += 8) {   // 2 independent gathers in flight
    int sA = cs[j], sB = cs[j + 4];
    uint4 uA = *(const uint4*)(XL + (size_t)sA * 128 + 8 * sl);
    uint4 uB = *(const uint4*)(XL + (size_t)sB * 128 + 8 * sl);
    stepv(uA, xr, at, acc, den);
    stepv(uB, xr, at, acc, den);
  }
  if (j < end) {
    int sA = cs[j];
    uint4 uA = *(const uint4*)(XL + (size_t)sA * 128 + 8 * sl);
    stepv(uA, xr, at, acc, den);
  }
  // combine the 4 edge slots
  den += __shfl_xor(den, 16); den += __shfl_xor(den, 32);
#pragma unroll
  for (int i = 0; i < 4; ++i) {
    acc[i].x += __shfl_xor(acc[i].x, 16);
    acc[i].y += __shfl_xor(acc[i].y, 16);
    acc[i].x += __shfl_xor(acc[i].x, 32);
    acc[i].y += __shfl_xor(acc[i].y, 32);
  }
  float inv = 1.f / (den + 1e-16f);   // per-head denom (sl<8: h0, sl>=8: h1)
  f32x2 o[4];
#pragma unroll
  for (int i = 0; i < 4; ++i) {
    f32x2 a = acc[i] * inv;
    o[i].x = a.x + __shfl_xor(a.x, 8);   // head sum (valid for sl<8)
    o[i].y = a.y + __shfl_xor(a.y, 8);
    o[i] = 0.5f * o[i];                  // head mean
  }
  if (lane >= 8) return;
  const float* bp = bias + 8 * lane;
  float4 b0 = *(const float4*)bp, b1 = *(const float4*)(bp + 4);
  o[0].x += b0.x; o[0].y += b0.y; o[1].x += b0.z; o[1].y += b0.w;
  o[2].x += b1.x; o[2].y += b1.y; o[3].x += b1.z; o[3].y += b1.w;
  size_t oi = (size_t)d * 64 + 8 * lane;
  if (phase == 0) {
    *(float4*)(accum + oi) = make_float4(o[0].x, o[0].y, o[1].x, o[1].y);
    *(float4*)(accum + oi + 4) = make_float4(o[2].x, o[2].y, o[3].x, o[3].y);
    return;
  }
  float4 pa0 = *(const float4*)(accum + oi);
  float4 pa1 = *(const float4*)(accum + oi + 4);
  f32x2 v[4];
  v[0].x = 0.5f * (pa0.x + o[0].x); v[0].y = 0.5f * (pa0.y + o[0].y);
  v[1].x = 0.5f * (pa0.z + o[1].x); v[1].y = 0.5f * (pa0.w + o[1].y);
  v[2].x = 0.5f * (pa1.x + o[2].x); v[2].y = 0.5f * (pa1.y + o[2].y);
  v[3].x = 0.5f * (pa1.z + o[3].x); v[3].y = 0.5f * (pa1.w + o[3].y);
  if (do_relu) {
#pragma unroll
    for (int i = 0; i < 4; ++i) v[i] = vmax2(v[i], f32x2{0.f, 0.f});
  }
  if (outf) {
    *(float4*)(outf + oi) = make_float4(v[0].x, v[0].y, v[1].x, v[1].y);
    *(float4*)(outf + oi + 4) = make_float4(v[2].x, v[2].y, v[3].x, v[3].y);
  } else {
    uint4 pk;
    pk.x = packbf(v[0].x, v[0].y); pk.y = packbf(v[1].x, v[1].y);
    pk.z = packbf(v[2].x, v[2].y); pk.w = packbf(v[3].x, v[3].y);
    hout[(size_t)d * 8 + lane] = pk;
  }
}

extern "C" void kernel_launch(void* const* d_in, const int* in_sizes, int n_in,
                              void* d_out, int out_size, void* d_ws, size_t ws_size,
                              hipStream_t stream) {
  const float* x       = (const float*)d_in[0];
  const int*   e_adj   = (const int*)d_in[1];
  const int*   e_ray   = (const int*)d_in[2];
  const float* l1_Wl   = (const float*)d_in[3];
  const float* l1_bl   = (const float*)d_in[4];
  const float* l1_Wr   = (const float*)d_in[5];
  const float* l1_br   = (const float*)d_in[6];
  const float* l1_att  = (const float*)d_in[7];
  const float* l1_bias = (const float*)d_in[8];
  const float* l2_Wl   = (const float*)d_in[9];
  const float* l2_bl   = (const float*)d_in[10];
  const float* l2_Wr   = (const float*)d_in[11];
  const float* l2_br   = (const float*)d_in[12];
  const float* l2_att  = (const float*)d_in[13];
  const float* l2_bias = (const float*)d_in[14];
  float* out = (float*)d_out;

  char* w = (char*)d_ws;
  size_t off = 0;
  auto alloc = [&](size_t bytes) -> char* {
    char* p = w + off;
    off += (bytes + 255) & ~(size_t)255;
    return p;
  };
  bf16* XL0  = (bf16*)alloc((size_t)N_PAD * 128 * 2);
  bf16* XR0  = (bf16*)alloc((size_t)N_PAD * 128 * 2);
  bf16* XL1  = (bf16*)alloc((size_t)N_PAD * 128 * 2);
  bf16* XR1  = (bf16*)alloc((size_t)N_PAD * 128 * 2);
  bf16* HB   = (bf16*)alloc((size_t)N_PAD * 64 * 2);
  short* WT  = (short*)alloc(2 * 16384 * 2);
  int* RP0   = (int*)alloc((size_t)(N_NODES + 1) * 4);
  int* RP1   = (int*)alloc((size_t)(N_NODES + 1) * 4);
  int* FI0   = (int*)alloc((size_t)N_NODES * 4);
  int* FI1   = (int*)alloc((size_t)N_NODES * 4);
  int* CS0   = (int*)alloc((size_t)E_EDGES * 4);
  int* CS1   = (int*)alloc((size_t)E_EDGES * 4);
  int* DG0   = (int*)alloc((size_t)N_NODES * 4);
  int* DG1   = (int*)alloc((size_t)N_NODES * 4);
  int* BSUM  = (int*)alloc(2 * NBLK * 4);
  float* ACC = out;  // relation-0 partial lives in d_out; phase-1 reads before writing

  const int* src_adj = e_adj;
  const int* dst_adj = e_adj + E_EDGES;
  const int* src_ray = e_ray;
  const int* dst_ray = e_ray + E_EDGES;

  const int WNB = (N_NODES * 64) / 256;    // 25000 (one wave per node)
  const int MB  = N_PAD / 128;             // 782
  const int SB  = SLICE_BLOCKS * NSLICE;   // 4096

  // CSR build
  size_t dgspan = (size_t)((char*)DG1 - (char*)DG0) + (size_t)N_NODES * 4;
  hipMemsetAsync(DG0, 0, dgspan, stream);
  hist_sliced_k<<<SB, 256, 0, stream>>>(dst_adj, dst_ray, DG0, DG1);
  scan_blk_k<<<dim3(NBLK, 2), 1024, 0, stream>>>(DG0, DG1, RP0, RP1, BSUM);
  scan_top_k<<<2, 128, 0, stream>>>(BSUM, RP0, RP1);
  scan_add_k<<<dim3(NBLK, 2), 1024, 0, stream>>>(BSUM, RP0, RP1, FI0, FI1);
  scat_sliced_k<<<SB, 256, 0, stream>>>(src_adj, dst_adj, src_ray, dst_ray,
                                        FI0, FI1, CS0, CS1);
  wprep_k<<<128, 256, 0, stream>>>(l2_Wl, l2_Wr, WT);

  // ---- layer 1 (K=2): one transform dispatch, per-relation agg ----
  t1f_k<<<N_NODES, 256, 0, stream>>>(x, l1_Wl, l1_bl, l1_Wr, l1_br,
                                     XL0, XR0, XL1, XR1);
  agg1_k<<<WNB, 256, 0, stream>>>(RP0, CS0, XL0, XR0, l1_att, l1_bias,
                                  ACC, nullptr, nullptr, 0, 0);
  agg1_k<<<WNB, 256, 0, stream>>>(RP1, CS1, XL1, XR1, l1_att + 128, l1_bias + 64,
                                  ACC, (uint4*)HB, nullptr, 1, 1);

  // ---- layer 2 (K=64): one MFMA dispatch (gridDim.z=2), per-relation agg ----
  mfma_t_k<<<dim3(MB, 1, 2), 256, 0, stream>>>(HB, WT, l2_bl, l2_br,
                                               XL0, XR0, XL1, XR1);
  agg1_k<<<WNB, 256, 0, stream>>>(RP0, CS0, XL0, XR0, l2_att, l2_bias,
                                  ACC, nullptr, nullptr, 0, 0);
  agg1_k<<<WNB, 256, 0, stream>>>(RP1, CS1, XL1, XR1, l2_att + 128, l2_bias + 64,
                                  ACC, nullptr, out, 1, 0);
}

// Round 9
// 526.194 us; speedup vs baseline: 1.1899x; 1.1072x over previous
//
#include <hip/hip_runtime.h>
#include <hip/hip_bf16.h>

typedef __hip_bfloat16 bf16;
typedef unsigned int uint;
typedef unsigned short ushort;
typedef __attribute__((ext_vector_type(8))) short short8;  // 8 x bf16 (4 VGPRs)
typedef __attribute__((ext_vector_type(4))) float floatx4;

#define N_NODES 100000
#define N_PAD   100096   // multiple of 128 for the MFMA row tiling
#define E_EDGES 800000
#define NBLK    98       // ceil(N_NODES / 1024)
#define NSLICE  8        // one dst-slice per XCD (blockIdx % 8 ~ XCD id)
#define SLICE_N 12512    // ceil(N_NODES / NSLICE)
#define SLICE_BLOCKS 512 // blocks per slice row

static __device__ __forceinline__ uint packbf(float a, float b) {
  bf16 x = __float2bfloat16(a), y = __float2bfloat16(b);
  ushort ux = *reinterpret_cast<ushort*>(&x);
  ushort uy = *reinterpret_cast<ushort*>(&y);
  return (uint)ux | ((uint)uy << 16);
}
static __device__ __forceinline__ float lo16(uint u) { return __uint_as_float(u << 16); }
static __device__ __forceinline__ float hi16(uint u) { return __uint_as_float(u & 0xffff0000u); }

// ---------------- CSR build (by destination), XCD-sliced ----------------
__global__ void hist_sliced_k(const int* __restrict__ dst0, const int* __restrict__ dst1,
                              int* dg0, int* dg1) {
  int slice = blockIdx.x & (NSLICE - 1);
  int blk = blockIdx.x >> 3;
  int lo = slice * SLICE_N, hi = lo + SLICE_N;
  for (int i = blk * 256 + threadIdx.x; i < E_EDGES; i += SLICE_BLOCKS * 256) {
    int d0 = dst0[i];
    if (d0 >= lo && d0 < hi) atomicAdd(&dg0[d0], 1);
    int d1 = dst1[i];
    if (d1 >= lo && d1 < hi) atomicAdd(&dg1[d1], 1);
  }
}

__global__ void scat_sliced_k(const int* __restrict__ src0, const int* __restrict__ dst0,
                              const int* __restrict__ src1, const int* __restrict__ dst1,
                              int* fi0, int* fi1, int* cs0, int* cs1) {
  int slice = blockIdx.x & (NSLICE - 1);
  int blk = blockIdx.x >> 3;
  int lo = slice * SLICE_N, hi = lo + SLICE_N;
  for (int i = blk * 256 + threadIdx.x; i < E_EDGES; i += SLICE_BLOCKS * 256) {
    int d0 = dst0[i];
    if (d0 >= lo && d0 < hi) { int p = atomicAdd(&fi0[d0], 1); cs0[p] = src0[i]; }
    int d1 = dst1[i];
    if (d1 >= lo && d1 < hi) { int p = atomicAdd(&fi1[d1], 1); cs1[p] = src1[i]; }
  }
}

__global__ void scan_blk_k(const int* __restrict__ deg0, const int* __restrict__ deg1,
                           int* rp0, int* rp1, int* bsum) {
  __shared__ int s[1024];
  int r = blockIdx.y;
  const int* deg = r ? deg1 : deg0;
  int* rp = r ? rp1 : rp0;
  int i = blockIdx.x * 1024 + threadIdx.x;
  int v = (i < N_NODES) ? deg[i] : 0;
  s[threadIdx.x] = v;
  __syncthreads();
  for (int off = 1; off < 1024; off <<= 1) {
    int t = (threadIdx.x >= off) ? s[threadIdx.x - off] : 0;
    __syncthreads();
    s[threadIdx.x] += t;
    __syncthreads();
  }
  if (i < N_NODES) rp[i] = s[threadIdx.x] - v;
  if (threadIdx.x == 1023) bsum[r * NBLK + blockIdx.x] = s[1023];
}

__global__ void scan_top_k(int* bsum, int* rp0, int* rp1) {
  __shared__ int s[128];
  int r = blockIdx.x;
  int v = (threadIdx.x < NBLK) ? bsum[r * NBLK + threadIdx.x] : 0;
  s[threadIdx.x] = v;
  __syncthreads();
  for (int off = 1; off < 128; off <<= 1) {
    int t = (threadIdx.x >= off) ? s[threadIdx.x - off] : 0;
    __syncthreads();
    s[threadIdx.x] += t;
    __syncthreads();
  }
  if (threadIdx.x < NBLK) bsum[r * NBLK + threadIdx.x] = s[threadIdx.x] - v;
  if (threadIdx.x == 127) (r ? rp1 : rp0)[N_NODES] = s[127];
}

__global__ void scan_add_k(const int* __restrict__ bsum,
                           int* rp0, int* rp1, int* fi0, int* fi1) {
  int r = blockIdx.y;
  int i = blockIdx.x * 1024 + threadIdx.x;
  if (i >= N_NODES) return;
  int* rp = r ? rp1 : rp0;
  int* fi = r ? fi1 : fi0;
  int val = rp[i] + bsum[r * NBLK + blockIdx.x];
  rp[i] = val;
  fi[i] = val;
}

// ---------------- layer-2 weight prep: WT[rel][c][k] bf16 (transposed) ----------------
__global__ void wprep_k(const float* __restrict__ Wl, const float* __restrict__ Wr,
                        short* __restrict__ WT) {
  int id2 = blockIdx.x * 256 + threadIdx.x;
  int rel = id2 >> 14;
  int id = id2 & 16383;
  int c = id >> 6, k = id & 63;
  const float* W = (c < 128) ? (Wl + rel * 8192) : (Wr + rel * 8192);
  int cc = c & 127;
  bf16 b = __float2bfloat16(W[k * 128 + cc]);
  WT[rel * 16384 + c * 64 + k] = *reinterpret_cast<short*>(&b);
}

// ---------------- layer-2 transform, both relations via blockIdx.z ----------------
__global__ __launch_bounds__(256) void mfma_t_k(const bf16* __restrict__ HB,
                                                const short* __restrict__ WTb,
                                                const float* __restrict__ blb,
                                                const float* __restrict__ brb,
                                                bf16* __restrict__ XL0,
                                                bf16* __restrict__ XR0,
                                                bf16* __restrict__ XL1,
                                                bf16* __restrict__ XR1) {
  __shared__ short sW[256 * 72];
  int rel = blockIdx.z;
  const short* WT = WTb + rel * 16384;
  const float* bl = blb + rel * 128;
  const float* br = brb + rel * 128;
  bf16* XLp = rel ? XL1 : XL0;
  bf16* XRp = rel ? XR1 : XR0;
  int t = threadIdx.x;
#pragma unroll
  for (int i = 0; i < 8; ++i) {
    int chunk = t + i * 256;
    int c = chunk >> 3, off = (chunk & 7) * 8;
    *(short8*)(&sW[c * 72 + off]) = *(const short8*)(WT + chunk * 8);
  }
  __syncthreads();
  int wave = t >> 6, lane = t & 63;
  int q = lane >> 4, m = lane & 15;
  int rowbase = blockIdx.x * 128 + wave * 32;
  short8 afr[2][2];
#pragma unroll
  for (int rt = 0; rt < 2; ++rt)
#pragma unroll
    for (int kh = 0; kh < 2; ++kh) {
      size_t row = (size_t)(rowbase + rt * 16 + m);
      afr[rt][kh] = *(const short8*)((const short*)HB + row * 64 + kh * 32 + q * 8);
    }
  for (int ct = 0; ct < 16; ++ct) {
    int col = ct * 16 + m;
    short8 b0 = *(const short8*)(&sW[col * 72 + q * 8]);
    short8 b1 = *(const short8*)(&sW[col * 72 + 32 + q * 8]);
    float bias = (col < 128) ? bl[col] : br[col - 128];
    bf16* X = (col < 128) ? XLp : XRp;
    int c128 = col & 127;
#pragma unroll
    for (int rt = 0; rt < 2; ++rt) {
      floatx4 acc = {0.f, 0.f, 0.f, 0.f};
      acc = __builtin_amdgcn_mfma_f32_16x16x32_bf16(afr[rt][0], b0, acc, 0, 0, 0);
      acc = __builtin_amdgcn_mfma_f32_16x16x32_bf16(afr[rt][1], b1, acc, 0, 0, 0);
      int r0 = rowbase + rt * 16 + q * 4;
#pragma unroll
      for (int i2 = 0; i2 < 4; ++i2) {
        int row = r0 + i2;
        if (row < N_NODES)
          X[(size_t)row * 128 + c128] = __float2bfloat16(acc[i2] + bias);
      }
    }
  }
}

// ---------------- layer-1 agg via rank-2 trick (IN_DIM=2) ----------------
// xl[s] = x0s*w0 + x1s*w1 + bl  (128-ch, rank 2!). Per edge we gather only
// x[src] (8 B, L2-resident). Scores exact fp32; payload accumulates as
// A0=SUM(alpha*x0s), A1=SUM(alpha*x1s); out_head = A0*w0 + A1*w1 + S*bl
// (S=SUM(alpha): ==1 normally, ==0 for empty destinations).
// wave = 1 dst node; halves process even/odd edges; lane (l=lane&31) covers
// channels 4l..4l+3; head0 = l 0..15, head1 = l 16..31.
__global__ __launch_bounds__(256) void aggl1_k(
    const int* __restrict__ rp, const int* __restrict__ cs,
    const float* __restrict__ x,
    const float* __restrict__ Wl, const float* __restrict__ blp,
    const float* __restrict__ Wr, const float* __restrict__ brp,
    const float* __restrict__ att, const float* __restrict__ bias,
    float* __restrict__ accum, uint2* __restrict__ hout,
    int phase, int do_relu) {
  int d = (blockIdx.x * 256 + threadIdx.x) >> 6;
  int lane = threadIdx.x & 63;
  if (d >= N_NODES) return;
  int half = lane >> 5;
  int l = lane & 31;
  int c0 = 4 * l;
  float4 w0 = *(const float4*)(Wl + c0);          // src-transform rank-2 vectors
  float4 w1 = *(const float4*)(Wl + 128 + c0);
  float4 v0 = *(const float4*)(Wr + c0);          // dst-transform rank-2 vectors
  float4 v1 = *(const float4*)(Wr + 128 + c0);
  float4 bb = *(const float4*)(blp + c0);
  float4 rb = *(const float4*)(brp + c0);
  float4 aa = *(const float4*)(att + c0);
  float2 xd = *(const float2*)(x + 2 * d);
  // q_c(d) = bl_c + br_c + x0d*v0_c + x1d*v1_c
  float q0 = bb.x + rb.x + xd.x * v0.x + xd.y * v1.x;
  float q1 = bb.y + rb.y + xd.x * v0.y + xd.y * v1.y;
  float q2 = bb.z + rb.z + xd.x * v0.z + xd.y * v1.z;
  float q3 = bb.w + rb.w + xd.x * v0.w + xd.y * v1.w;
  float A0 = 0.f, A1 = 0.f, den = 0.f;
  int beg = rp[d], end = rp[d + 1];
  int j = beg + half;

#define L1_EDGE(XS)                                                          \
  {                                                                          \
    float e0 = q0 + XS.x * w0.x + XS.y * w1.x; e0 = fmaxf(e0, 0.2f * e0);    \
    float e1 = q1 + XS.x * w0.y + XS.y * w1.y; e1 = fmaxf(e1, 0.2f * e1);    \
    float e2 = q2 + XS.x * w0.z + XS.y * w1.z; e2 = fmaxf(e2, 0.2f * e2);    \
    float e3 = q3 + XS.x * w0.w + XS.y * w1.w; e3 = fmaxf(e3, 0.2f * e3);    \
    float p = e0 * aa.x + e1 * aa.y + e2 * aa.z + e3 * aa.w;                 \
    p += __shfl_xor(p, 1);                                                   \
    p += __shfl_xor(p, 2);                                                   \
    p += __shfl_xor(p, 4);                                                   \
    p += __shfl_xor(p, 8);                                                   \
    float ex = __expf(p);                                                    \
    den += ex; A0 += ex * XS.x; A1 += ex * XS.y;                             \
  }

  for (; j + 2 < end; j += 4) {
    int sA = cs[j], sB = cs[j + 2];
    float2 xA = *(const float2*)(x + 2 * sA);
    float2 xB = *(const float2*)(x + 2 * sB);
    L1_EDGE(xA);
    L1_EDGE(xB);
  }
  for (; j < end; j += 2) {
    int sA = cs[j];
    float2 xA = *(const float2*)(x + 2 * sA);
    L1_EDGE(xA);
  }
#undef L1_EDGE
  // combine edge-parity halves
  den += __shfl_xor(den, 32);
  A0 += __shfl_xor(A0, 32);
  A1 += __shfl_xor(A1, 32);
  float inv = 1.f / (den + 1e-16f);
  float S = den * inv;          // SUM(alpha): 1 normally, 0 for empty dst
  float a0 = A0 * inv, a1 = A1 * inv;
  // reconstruct per-head output channels for this lane
  float o0 = a0 * w0.x + a1 * w1.x + S * bb.x;
  float o1 = a0 * w0.y + a1 * w1.y + S * bb.y;
  float o2 = a0 * w0.z + a1 * w1.z + S * bb.z;
  float o3 = a0 * w0.w + a1 * w1.w + S * bb.w;
  // head mean: lane l (<16, h0 per-head ch 4l+i) pairs with l+16 (h1 same)
  o0 = 0.5f * (o0 + __shfl_xor(o0, 16));
  o1 = 0.5f * (o1 + __shfl_xor(o1, 16));
  o2 = 0.5f * (o2 + __shfl_xor(o2, 16));
  o3 = 0.5f * (o3 + __shfl_xor(o3, 16));
  if (lane >= 16) return;
  int cc = 4 * lane;
  o0 += bias[cc]; o1 += bias[cc + 1]; o2 += bias[cc + 2]; o3 += bias[cc + 3];
  size_t oi = (size_t)d * 64 + cc;
  if (phase == 0) {
    *(float4*)(accum + oi) = make_float4(o0, o1, o2, o3);
  } else {
    float4 pa = *(const float4*)(accum + oi);
    float v0_ = 0.5f * (pa.x + o0);
    float v1_ = 0.5f * (pa.y + o1);
    float v2_ = 0.5f * (pa.z + o2);
    float v3_ = 0.5f * (pa.w + o3);
    if (do_relu) {
      v0_ = fmaxf(v0_, 0.f); v1_ = fmaxf(v1_, 0.f);
      v2_ = fmaxf(v2_, 0.f); v3_ = fmaxf(v3_, 0.f);
    }
    hout[(size_t)d * 16 + lane] = make_uint2(packbf(v0_, v1_), packbf(v2_, v3_));
  }
}

// ---------------- layer-2 agg (r6-proven): 32 lanes/edge, uint2, scalar f32 ----------------
struct EdgeAcc { float a0, a1, a2, a3, den; };

static __device__ __forceinline__ void edge_step(
    uint2 u, float xr0, float xr1, float xr2, float xr3,
    float at0, float at1, float at2, float at3, EdgeAcc& A) {
  float x0 = lo16(u.x), x1 = hi16(u.x), x2 = lo16(u.y), x3 = hi16(u.y);
  float e0 = x0 + xr0; e0 = e0 > 0.f ? e0 : 0.2f * e0;
  float e1 = x1 + xr1; e1 = e1 > 0.f ? e1 : 0.2f * e1;
  float e2 = x2 + xr2; e2 = e2 > 0.f ? e2 : 0.2f * e2;
  float e3 = x3 + xr3; e3 = e3 > 0.f ? e3 : 0.2f * e3;
  float p = e0 * at0 + e1 * at1 + e2 * at2 + e3 * at3;
  p += __shfl_xor(p, 1);
  p += __shfl_xor(p, 2);
  p += __shfl_xor(p, 4);
  p += __shfl_xor(p, 8);        // 16-lane head-group total
  float ex = __expf(p);
  A.den += ex;
  A.a0 += ex * x0; A.a1 += ex * x1; A.a2 += ex * x2; A.a3 += ex * x3;
}

__global__ __launch_bounds__(256) void aggh_k(
    const int* __restrict__ rp, const int* __restrict__ cs,
    const bf16* __restrict__ XL, const bf16* __restrict__ XR,
    const float* __restrict__ att, const float* __restrict__ bias,
    float* __restrict__ accum, float* __restrict__ outf, int phase) {
  int d = (blockIdx.x * 256 + threadIdx.x) >> 6;
  int lane = threadIdx.x & 63;
  if (d >= N_NODES) return;
  int half = lane >> 5;
  int l = lane & 31;
  const float* at = att + 4 * l;
  float at0 = at[0], at1 = at[1], at2 = at[2], at3 = at[3];
  uint2 ur = *(const uint2*)(XR + (size_t)d * 128 + 4 * l);
  float xr0 = lo16(ur.x), xr1 = hi16(ur.x), xr2 = lo16(ur.y), xr3 = hi16(ur.y);
  EdgeAcc A = {0.f, 0.f, 0.f, 0.f, 0.f};
  int beg = rp[d], end = rp[d + 1];
  int j = beg + half;
  for (; j + 2 < end; j += 4) {
    int sA = cs[j], sB = cs[j + 2];
    uint2 uA = *(const uint2*)(XL + (size_t)sA * 128 + 4 * l);
    uint2 uB = *(const uint2*)(XL + (size_t)sB * 128 + 4 * l);
    edge_step(uA, xr0, xr1, xr2, xr3, at0, at1, at2, at3, A);
    edge_step(uB, xr0, xr1, xr2, xr3, at0, at1, at2, at3, A);
  }
  for (; j < end; j += 2) {
    int s = cs[j];
    uint2 u = *(const uint2*)(XL + (size_t)s * 128 + 4 * l);
    edge_step(u, xr0, xr1, xr2, xr3, at0, at1, at2, at3, A);
  }
  A.den += __shfl_xor(A.den, 32);
  A.a0 += __shfl_xor(A.a0, 32);
  A.a1 += __shfl_xor(A.a1, 32);
  A.a2 += __shfl_xor(A.a2, 32);
  A.a3 += __shfl_xor(A.a3, 32);
  float inv = 1.f / (A.den + 1e-16f);
  A.a0 *= inv; A.a1 *= inv; A.a2 *= inv; A.a3 *= inv;
  float o0 = 0.5f * (A.a0 + __shfl_xor(A.a0, 16));
  float o1 = 0.5f * (A.a1 + __shfl_xor(A.a1, 16));
  float o2 = 0.5f * (A.a2 + __shfl_xor(A.a2, 16));
  float o3 = 0.5f * (A.a3 + __shfl_xor(A.a3, 16));
  if (lane >= 16) return;
  int c0 = 4 * lane;
  o0 += bias[c0]; o1 += bias[c0 + 1]; o2 += bias[c0 + 2]; o3 += bias[c0 + 3];
  size_t oi = (size_t)d * 64 + c0;
  if (phase == 0) {
    *(float4*)(accum + oi) = make_float4(o0, o1, o2, o3);
  } else {
    float4 pa = *(const float4*)(accum + oi);
    float v0 = 0.5f * (pa.x + o0);
    float v1 = 0.5f * (pa.y + o1);
    float v2 = 0.5f * (pa.z + o2);
    float v3 = 0.5f * (pa.w + o3);
    *(float4*)(outf + oi) = make_float4(v0, v1, v2, v3);
  }
}

extern "C" void kernel_launch(void* const* d_in, const int* in_sizes, int n_in,
                              void* d_out, int out_size, void* d_ws, size_t ws_size,
                              hipStream_t stream) {
  const float* x       = (const float*)d_in[0];
  const int*   e_adj   = (const int*)d_in[1];
  const int*   e_ray   = (const int*)d_in[2];
  const float* l1_Wl   = (const float*)d_in[3];
  const float* l1_bl   = (const float*)d_in[4];
  const float* l1_Wr   = (const float*)d_in[5];
  const float* l1_br   = (const float*)d_in[6];
  const float* l1_att  = (const float*)d_in[7];
  const float* l1_bias = (const float*)d_in[8];
  const float* l2_Wl   = (const float*)d_in[9];
  const float* l2_bl   = (const float*)d_in[10];
  const float* l2_Wr   = (const float*)d_in[11];
  const float* l2_br   = (const float*)d_in[12];
  const float* l2_att  = (const float*)d_in[13];
  const float* l2_bias = (const float*)d_in[14];
  float* out = (float*)d_out;

  char* w = (char*)d_ws;
  size_t off = 0;
  auto alloc = [&](size_t bytes) -> char* {
    char* p = w + off;
    off += (bytes + 255) & ~(size_t)255;
    return p;
  };
  bf16* XL0  = (bf16*)alloc((size_t)N_PAD * 128 * 2);   // layer-2 transforms only
  bf16* XR0  = (bf16*)alloc((size_t)N_PAD * 128 * 2);
  bf16* XL1  = (bf16*)alloc((size_t)N_PAD * 128 * 2);
  bf16* XR1  = (bf16*)alloc((size_t)N_PAD * 128 * 2);
  bf16* HB   = (bf16*)alloc((size_t)N_PAD * 64 * 2);
  short* WT  = (short*)alloc(2 * 16384 * 2);
  int* RP0   = (int*)alloc((size_t)(N_NODES + 1) * 4);
  int* RP1   = (int*)alloc((size_t)(N_NODES + 1) * 4);
  int* FI0   = (int*)alloc((size_t)N_NODES * 4);
  int* FI1   = (int*)alloc((size_t)N_NODES * 4);
  int* CS0   = (int*)alloc((size_t)E_EDGES * 4);
  int* CS1   = (int*)alloc((size_t)E_EDGES * 4);
  int* DG0   = (int*)alloc((size_t)N_NODES * 4);
  int* DG1   = (int*)alloc((size_t)N_NODES * 4);
  int* BSUM  = (int*)alloc(2 * NBLK * 4);
  float* ACC = out;  // relation-0 partial lives in d_out; phase-1 reads before writing

  const int* src_adj = e_adj;
  const int* dst_adj = e_adj + E_EDGES;
  const int* src_ray = e_ray;
  const int* dst_ray = e_ray + E_EDGES;

  const int WNB = (N_NODES * 64) / 256;    // 25000 (one wave per node)
  const int MB  = N_PAD / 128;             // 782
  const int SB  = SLICE_BLOCKS * NSLICE;   // 4096

  // CSR build
  size_t dgspan = (size_t)((char*)DG1 - (char*)DG0) + (size_t)N_NODES * 4;
  hipMemsetAsync(DG0, 0, dgspan, stream);
  hist_sliced_k<<<SB, 256, 0, stream>>>(dst_adj, dst_ray, DG0, DG1);
  scan_blk_k<<<dim3(NBLK, 2), 1024, 0, stream>>>(DG0, DG1, RP0, RP1, BSUM);
  scan_top_k<<<2, 128, 0, stream>>>(BSUM, RP0, RP1);
  scan_add_k<<<dim3(NBLK, 2), 1024, 0, stream>>>(BSUM, RP0, RP1, FI0, FI1);
  scat_sliced_k<<<SB, 256, 0, stream>>>(src_adj, dst_adj, src_ray, dst_ray,
                                        FI0, FI1, CS0, CS1);
  wprep_k<<<128, 256, 0, stream>>>(l2_Wl, l2_Wr, WT);

  // ---- layer 1 (rank-2 trick): NO transforms, gathers raw x ----
  aggl1_k<<<WNB, 256, 0, stream>>>(RP0, CS0, x, l1_Wl, l1_bl, l1_Wr, l1_br,
                                   l1_att, l1_bias, ACC, nullptr, 0, 0);
  aggl1_k<<<WNB, 256, 0, stream>>>(RP1, CS1, x, l1_Wl + 256, l1_bl + 128,
                                   l1_Wr + 256, l1_br + 128, l1_att + 128,
                                   l1_bias + 64, ACC, (uint2*)HB, 1, 1);

  // ---- layer 2 (K=64): one MFMA dispatch (gridDim.z=2), per-relation agg ----
  mfma_t_k<<<dim3(MB, 1, 2), 256, 0, stream>>>(HB, WT, l2_bl, l2_br,
                                               XL0, XR0, XL1, XR1);
  aggh_k<<<WNB, 256, 0, stream>>>(RP0, CS0, XL0, XR0, l2_att, l2_bias,
                                  ACC, nullptr, 0);
  aggh_k<<<WNB, 256, 0, stream>>>(RP1, CS1, XL1, XR1, l2_att + 128, l2_bias + 64,
                                  ACC, out, 1);
}